// Round 5
// baseline (137.680 us; speedup 1.0000x reference)
//
#include <hip/hip_runtime.h>
#include <stdint.h>

// ---------------------------------------------------------------------------
// OutputLayerReverseSegments, round 5: token-aligned + private partial
// buffers (no atomics).
// out[b,f,c] = sum_i x[b,c,t_i(f),:] . W_i[p_i(f),:] + sum_i b_i[p_i(f)]
// B=64, C=64, T=63, D=256, F=720, partitions k = {1,2,4,8,16,32}
//
// Wave = (token tok, 16-c tile): loads its single x token once into bf16
// register fragments, sweeps the part's f-subtiles vs a pre-packed bf16 W
// fragment table (2.4 MB, L2-resident), and STORES (not atomics) into a
// per-partition-level fp32 partial buffer buf[i] in d_ws (tokens in one
// partition level cover disjoint f -> no write conflicts). A reduce kernel
// computes out = sum_i b_i[pos(i,f)] + sum_i buf_i, fully coalesced.
// x HBM traffic = 264 MB exactly. Fallbacks: atomic path (ws >= 2.4 MB),
// direct path (tiny ws).
// ---------------------------------------------------------------------------

#define FDIM 720
#define DDIM 256
#define TDIM 63
#define NSUBTOT 299                              // sum over (i,j) of ceil(len/16)
#define TAB_BYTES ((size_t)NSUBTOT * 8 * 1024)   // 2,449,408
#define OUTELEMS ((size_t)64 * FDIM * 64)        // 2,949,120
#define BUF_OFF   TAB_BYTES
#define WS_NEED_BUF (TAB_BYTES + 6 * OUTELEMS * 4)   // ~73.2 MB
#define WS_NEED_TAB (TAB_BYTES + FDIM * 4)           // atomic path (bias tab unused now)

typedef __attribute__((ext_vector_type(8))) short short8;
typedef __attribute__((ext_vector_type(4))) float f32x4;

// pack 2 f32 -> 2 bf16 (round-half-up) in one u32: 2 adds + 1 v_perm
__device__ __forceinline__ uint32_t pkru(float a, float b) {
    uint32_t ua = __builtin_bit_cast(uint32_t, a) + 0x8000u;
    uint32_t ub = __builtin_bit_cast(uint32_t, b) + 0x8000u;
    return __builtin_amdgcn_perm(ub, ua, 0x07060302u);
}
__device__ __forceinline__ short8 loadpack(const float* p) {
    float4 v0 = *(const float4*)p;
    float4 v1 = *(const float4*)(p + 4);
    uint4 u;
    u.x = pkru(v0.x, v0.y);
    u.y = pkru(v0.z, v0.w);
    u.z = pkru(v1.x, v1.y);
    u.w = pkru(v1.z, v1.w);
    return __builtin_bit_cast(short8, u);
}

// partition index / position within part, for partition i at forecast f
__device__ __forceinline__ void jpos(int i, int f, int& j, int& pos) {
    switch (i) {
        case 0: j = 0;       pos = f;            break;
        case 1: j = f / 360; pos = f - 360 * j;  break;
        case 2: j = f / 180; pos = f - 180 * j;  break;
        case 3: j = f / 90;  pos = f - 90 * j;   break;
        case 4: j = f / 45;  pos = f - 45 * j;   break;
        default:
            if (f < 368) { j = f / 23;  pos = f - 23 * j; }
            else { int g = f - 368; int q = g / 22; j = 16 + q; pos = g - 22 * q; }
            break;
    }
}

// per-token parameters (branchy: no runtime-indexed arrays -> no scratch)
__device__ __forceinline__ void tok_params(int tok, int& pi, int& len, int& ns,
                                           int& start, int& tabsub) {
    if (tok < 1)       { pi = 0; len = 720; ns = 45; start = 0;
                         tabsub = 0; }
    else if (tok < 3)  { int j = tok - 1;  pi = 1; len = 360; ns = 23; start = 360 * j;
                         tabsub = 45 + j * 23; }
    else if (tok < 7)  { int j = tok - 3;  pi = 2; len = 180; ns = 12; start = 180 * j;
                         tabsub = 91 + j * 12; }
    else if (tok < 15) { int j = tok - 7;  pi = 3; len = 90;  ns = 6;  start = 90 * j;
                         tabsub = 139 + j * 6; }
    else if (tok < 31) { int j = tok - 15; pi = 4; len = 45;  ns = 3;  start = 45 * j;
                         tabsub = 187 + j * 3; }
    else               { int j = tok - 31; pi = 5;
                         len = (j < 16) ? 23 : 22;
                         start = (j < 16) ? 23 * j : 368 + 22 * (j - 16);
                         ns = 2; tabsub = 235 + j * 2; }
}

// ---------------------------------------------------------------------------
// Prep: build bf16 W fragment table in d_ws.
// frag fid = (tabsub(i,j) + s)*8 + ks; lane*16B holds
// W_i[s*16+(lane&15)][ks*32+(lane>>4)*8 ..+8) as bf16 (zeros if row >= len).
// ---------------------------------------------------------------------------
__global__ __launch_bounds__(256) void olrs_prep(
    const float* __restrict__ W0, const float* __restrict__ W1,
    const float* __restrict__ W2, const float* __restrict__ W3,
    const float* __restrict__ W4, const float* __restrict__ W5,
    char* __restrict__ ws)
{
    const int gid  = blockIdx.x * 256 + threadIdx.x;
    const int lane = gid & 63;
    const int fid  = gid >> 6;
    if (fid >= NSUBTOT * 8) return;
    const int ks = fid & 7;
    const int g  = fid >> 3;      // global subtile 0..298

    int len; const float* W;
    int s;
    if (g < 45)       { W = W0; len = 720; s = g; }
    else if (g < 91)  { int g2 = g - 45;  W = W1; len = 360; s = g2 % 23; }
    else if (g < 139) { int g2 = g - 91;  W = W2; len = 180; s = g2 % 12; }
    else if (g < 187) { int g2 = g - 139; W = W3; len = 90;  s = g2 % 6; }
    else if (g < 235) { int g2 = g - 187; W = W4; len = 45;  s = g2 % 3; }
    else              { int g2 = g - 235; W = W5; int j = g2 >> 1;
                        len = (j < 16) ? 23 : 22; s = g2 & 1; }

    const int m15  = lane & 15;
    const int koct = lane >> 4;
    const int pos  = s * 16 + m15;
    uint4 u = {0u, 0u, 0u, 0u};
    if (pos < len) {
        const float* src = W + (size_t)pos * DDIM + ks * 32 + koct * 8;
        float4 v0 = *(const float4*)src;
        float4 v1 = *(const float4*)(src + 4);
        u.x = pkru(v0.x, v0.y);
        u.y = pkru(v0.z, v0.w);
        u.z = pkru(v1.x, v1.y);
        u.w = pkru(v1.z, v1.w);
    }
    *(uint4*)(ws + (size_t)fid * 1024 + lane * 16) = u;
}

// ---------------------------------------------------------------------------
// Main (buffer flavor): wave = (tok, ntile). x token in registers, sweep
// f-subtiles, PLAIN STORES into per-partition partial buffer.
// ---------------------------------------------------------------------------
__global__ __launch_bounds__(256) void olrs_main_buf(
    const float* __restrict__ x,
    char* __restrict__ ws)
{
    const int wid   = blockIdx.x * 4 + (threadIdx.x >> 6);
    const int lane  = threadIdx.x & 63;
    const int tok   = wid >> 8;      // 0..62  (long parts first)
    const int ntile = wid & 255;
    const int b     = ntile >> 2;
    const int c0    = (ntile & 3) << 4;
    const int m15   = lane & 15;
    const int koct  = lane >> 4;

    int pi, len, ns, start, tabsub;
    tok_params(tok, pi, len, ns, start, tabsub);

    // ---- load this wave's x token once: 16c x 256d fp32 -> bf16 frags
    const float* xp = x + (((size_t)(b * 64 + c0 + m15)) * TDIM + tok) * DDIM;
    short8 xf[8];
    #pragma unroll
    for (int ks = 0; ks < 8; ks++)
        xf[ks] = loadpack(xp + ks * 32 + koct * 8);

    const char* tab = ws + (size_t)tabsub * 8192 + lane * 16;
    float* buf = (float*)(ws + BUF_OFF) + (size_t)pi * OUTELEMS;
    float* obase = buf + ((size_t)b * FDIM + start) * 64 + c0 + m15;

    for (int s = 0; s < ns; s++) {
        f32x4 a0 = {0.f, 0.f, 0.f, 0.f};
        f32x4 a1 = {0.f, 0.f, 0.f, 0.f};
        const char* tsub = tab + (size_t)s * 8192;
        #pragma unroll
        for (int ks = 0; ks < 8; ks += 2) {
            short8 w0 = *(const short8*)(tsub + ks * 1024);
            short8 w1 = *(const short8*)(tsub + (ks + 1) * 1024);
            a0 = __builtin_amdgcn_mfma_f32_16x16x32_bf16(w0, xf[ks],     a0, 0, 0, 0);
            a1 = __builtin_amdgcn_mfma_f32_16x16x32_bf16(w1, xf[ks + 1], a1, 0, 0, 0);
        }
        const int fl0 = s * 16 + koct * 4;
        #pragma unroll
        for (int rg = 0; rg < 4; rg++) {
            const int fl = fl0 + rg;
            if (fl < len) obase[(size_t)fl * 64] = a0[rg] + a1[rg];
        }
    }
}

// ---------------------------------------------------------------------------
// Reduce: out = sum_i b_i[pos(i,f)] + sum_i buf_i.  Coalesced float4.
// Fully overwrites out -> replay-safe.
// ---------------------------------------------------------------------------
__global__ __launch_bounds__(256) void olrs_reduce(
    const char* __restrict__ ws,
    const float* __restrict__ b0, const float* __restrict__ b1,
    const float* __restrict__ b2, const float* __restrict__ b3,
    const float* __restrict__ b4, const float* __restrict__ b5,
    float* __restrict__ out)
{
    const size_t gid  = (size_t)blockIdx.x * 256 + threadIdx.x;
    const size_t base = gid * 4;
    if (base >= OUTELEMS) return;
    const int f = (int)((base >> 6) % FDIM);

    int j, p;
    float bias = b0[f];
    jpos(1, f, j, p); bias += b1[p];
    jpos(2, f, j, p); bias += b2[p];
    jpos(3, f, j, p); bias += b3[p];
    jpos(4, f, j, p); bias += b4[p];
    jpos(5, f, j, p); bias += b5[p];

    const float* bufs = (const float*)(ws + BUF_OFF);
    float sx = bias, sy = bias, sz = bias, sw = bias;
    #pragma unroll
    for (int i = 0; i < 6; i++) {
        float4 v = *(const float4*)(bufs + (size_t)i * OUTELEMS + base);
        sx += v.x; sy += v.y; sz += v.z; sw += v.w;
    }
    float4 o = {sx, sy, sz, sw};
    *(float4*)(out + base) = o;
}

// ---------------------------------------------------------------------------
// Fallback flavor A (ws >= TAB only): round-4 atomic path.
// ---------------------------------------------------------------------------
__global__ __launch_bounds__(256) void olrs_init(
    const float* __restrict__ b0, const float* __restrict__ b1,
    const float* __restrict__ b2, const float* __restrict__ b3,
    const float* __restrict__ b4, const float* __restrict__ b5,
    float* __restrict__ out)
{
    const int gid = blockIdx.x * 256 + threadIdx.x;
    if (gid >= (int)OUTELEMS) return;
    const int f = (gid >> 6) % FDIM;
    int j, p;
    float s = b0[f];
    jpos(1, f, j, p); s += b1[p];
    jpos(2, f, j, p); s += b2[p];
    jpos(3, f, j, p); s += b3[p];
    jpos(4, f, j, p); s += b4[p];
    jpos(5, f, j, p); s += b5[p];
    out[gid] = s;
}

__global__ __launch_bounds__(256) void olrs_main_atomic(
    const float* __restrict__ x,
    const char* __restrict__ ws,
    float* __restrict__ out)
{
    const int wid   = blockIdx.x * 4 + (threadIdx.x >> 6);
    const int lane  = threadIdx.x & 63;
    const int tok   = wid >> 8;
    const int ntile = wid & 255;
    const int b     = ntile >> 2;
    const int c0    = (ntile & 3) << 4;
    const int m15   = lane & 15;
    const int koct  = lane >> 4;

    int pi, len, ns, start, tabsub;
    tok_params(tok, pi, len, ns, start, tabsub);

    const float* xp = x + (((size_t)(b * 64 + c0 + m15)) * TDIM + tok) * DDIM;
    short8 xf[8];
    #pragma unroll
    for (int ks = 0; ks < 8; ks++)
        xf[ks] = loadpack(xp + ks * 32 + koct * 8);

    const char* tab = ws + (size_t)tabsub * 8192 + lane * 16;
    float* obase = out + ((size_t)b * FDIM + start) * 64 + c0 + m15;

    for (int s = 0; s < ns; s++) {
        f32x4 a0 = {0.f, 0.f, 0.f, 0.f};
        f32x4 a1 = {0.f, 0.f, 0.f, 0.f};
        const char* tsub = tab + (size_t)s * 8192;
        #pragma unroll
        for (int ks = 0; ks < 8; ks += 2) {
            short8 w0 = *(const short8*)(tsub + ks * 1024);
            short8 w1 = *(const short8*)(tsub + (ks + 1) * 1024);
            a0 = __builtin_amdgcn_mfma_f32_16x16x32_bf16(w0, xf[ks],     a0, 0, 0, 0);
            a1 = __builtin_amdgcn_mfma_f32_16x16x32_bf16(w1, xf[ks + 1], a1, 0, 0, 0);
        }
        const int fl0 = s * 16 + koct * 4;
        #pragma unroll
        for (int rg = 0; rg < 4; rg++) {
            const int fl = fl0 + rg;
            if (fl < len) atomicAdd(obase + (size_t)fl * 64, a0[rg] + a1[rg]);
        }
    }
}

// ---------------------------------------------------------------------------
// Fallback flavor B (tiny ws): wave-independent direct-load kernel.
// ---------------------------------------------------------------------------
__device__ __forceinline__ int startf(int i, int j) {
    switch (i) {
        case 0: return 0;
        case 1: return 360 * j;
        case 2: return 180 * j;
        case 3: return 90 * j;
        case 4: return 45 * j;
        default: return (j < 16) ? 23 * j : 368 + 22 * (j - 16);
    }
}

__global__ __launch_bounds__(256) void olrs_fb(
    const float* __restrict__ x,
    const float* __restrict__ W0, const float* __restrict__ b0,
    const float* __restrict__ W1, const float* __restrict__ b1,
    const float* __restrict__ W2, const float* __restrict__ b2,
    const float* __restrict__ W3, const float* __restrict__ b3,
    const float* __restrict__ W4, const float* __restrict__ b4,
    const float* __restrict__ W5, const float* __restrict__ b5,
    float* __restrict__ out)
{
    const float* Wp[6] = {W0, W1, W2, W3, W4, W5};
    const float* bp[6] = {b0, b1, b2, b3, b4, b5};
    const int TB[6] = {0, 1, 3, 7, 15, 31};

    const int wid  = blockIdx.x * 4 + (threadIdx.x >> 6);
    const int lane = threadIdx.x & 63;
    const int ft   = wid % 45;
    const int bc   = wid / 45;
    const int b    = bc >> 2;
    const int c0   = (bc & 3) << 4;
    const int f0   = ft << 4;
    const int m15  = lane & 15;
    const int koct = lane >> 4;
    const size_t xrow = (size_t)(b * 64 + c0 + m15) * TDIM;

    f32x4 acc = {0.f, 0.f, 0.f, 0.f};
    #pragma unroll
    for (int i = 0; i < 6; i++) {
        int jlo, plo, jhi, phi;
        jpos(i, f0, jlo, plo);
        jpos(i, f0 + 15, jhi, phi);
        const bool cross = (jhi > jlo);
        const int fb = cross ? (startf(i, jhi) - f0) : 16;
        const float* xlo = x + (xrow + TB[i] + jlo) * DDIM;
        const float* xhi = x + (xrow + TB[i] + jhi) * DDIM;
        int jw, pw;
        jpos(i, f0 + m15, jw, pw);
        const float* wsrc = Wp[i] + (size_t)pw * DDIM;
        #pragma unroll
        for (int ks = 0; ks < 8; ks++) {
            const int d0 = ks * 32 + koct * 8;
            short8 a = loadpack(wsrc + d0);
            short8 blo = loadpack(xlo + d0);
            if (!cross) {
                acc = __builtin_amdgcn_mfma_f32_16x16x32_bf16(a, blo, acc, 0, 0, 0);
            } else {
                short8 bhi = loadpack(xhi + d0);
                short8 z;
                #pragma unroll
                for (int q = 0; q < 8; q++) z[q] = 0;
                short8 alo = (m15 < fb) ? a : z;
                short8 ahi = (m15 < fb) ? z : a;
                acc = __builtin_amdgcn_mfma_f32_16x16x32_bf16(alo, blo, acc, 0, 0, 0);
                acc = __builtin_amdgcn_mfma_f32_16x16x32_bf16(ahi, bhi, acc, 0, 0, 0);
            }
        }
    }
    #pragma unroll
    for (int rg = 0; rg < 4; rg++) {
        const int f = f0 + koct * 4 + rg;
        float bias = 0.f;
        #pragma unroll
        for (int i = 0; i < 6; i++) {
            int j, pos;
            jpos(i, f, j, pos);
            bias += bp[i][pos];
        }
        out[((size_t)b * FDIM + f) * 64 + c0 + m15] = acc[rg] + bias;
    }
}

extern "C" void kernel_launch(void* const* d_in, const int* in_sizes, int n_in,
                              void* d_out, int out_size, void* d_ws, size_t ws_size,
                              hipStream_t stream) {
    (void)in_sizes; (void)n_in; (void)out_size;

    const float* x  = (const float*)d_in[0];
    const float* W0 = (const float*)d_in[1];
    const float* b0 = (const float*)d_in[2];
    const float* W1 = (const float*)d_in[3];
    const float* b1 = (const float*)d_in[4];
    const float* W2 = (const float*)d_in[5];
    const float* b2 = (const float*)d_in[6];
    const float* W3 = (const float*)d_in[7];
    const float* b3 = (const float*)d_in[8];
    const float* W4 = (const float*)d_in[9];
    const float* b4 = (const float*)d_in[10];
    const float* W5 = (const float*)d_in[11];
    const float* b5 = (const float*)d_in[12];
    float* out = (float*)d_out;

    if (ws_size >= WS_NEED_BUF) {
        char* ws = (char*)d_ws;
        olrs_prep<<<dim3((NSUBTOT * 8 * 64 + 255) / 256), dim3(256), 0, stream>>>(
            W0, W1, W2, W3, W4, W5, ws);
        olrs_main_buf<<<dim3(63 * 256 / 4), dim3(256), 0, stream>>>(x, ws);
        olrs_reduce<<<dim3((unsigned)((OUTELEMS / 4 + 255) / 256)), dim3(256), 0, stream>>>(
            ws, b0, b1, b2, b3, b4, b5, out);
    } else if (ws_size >= WS_NEED_TAB) {
        char* ws = (char*)d_ws;
        olrs_prep<<<dim3((NSUBTOT * 8 * 64 + 255) / 256), dim3(256), 0, stream>>>(
            W0, W1, W2, W3, W4, W5, ws);
        olrs_init<<<dim3((unsigned)(OUTELEMS / 256)), dim3(256), 0, stream>>>(
            b0, b1, b2, b3, b4, b5, out);
        olrs_main_atomic<<<dim3(63 * 256 / 4), dim3(256), 0, stream>>>(x, ws, out);
    } else {
        olrs_fb<<<dim3(45 * 256), dim3(256), 0, stream>>>(
            x, W0, b0, W1, b1, W2, b2, W3, b3, W4, b4, W5, b5, out);
    }
}

// Round 6
// 104.193 us; speedup vs baseline: 1.3214x; 1.3214x over previous
//
#include <hip/hip_runtime.h>
#include <stdint.h>

// ---------------------------------------------------------------------------
// OutputLayerReverseSegments, round 6: balanced chunks + atomic merge.
// out[b,f,c] = sum_i x[b,c,t_i(f),:] . W_i[p_i(f),:] + sum_i b_i[p_i(f)]
// B=64, C=64, T=63, D=256, F=720, partitions k = {1,2,4,8,16,32}
//
// Round-5 post-mortem: atomics == plain stores (not the limiter); the real
// limiter is load imbalance (2..45 subtiles per wave -> 36% occupancy,
// idle tail). Fix: work unit = (chunk of <=6 subtiles, 16-c tile), 80
// chunks covering all 63 tokens -> 20,480 near-uniform waves. Each wave
// loads its token's 16c x 256d x-slab once into bf16 register fragments
// (chunk-siblings re-hit L2/L3), MFMAs against the pre-packed bf16 W
// fragment table (2.4 MB, L2-resident), atomicAdds into out. Init kernel
// pre-writes out = bias(f) (full overwrite -> replay-safe).
// ---------------------------------------------------------------------------

#define FDIM 720
#define DDIM 256
#define TDIM 63
#define NSUBTOT 299                              // sum over (i,j) of ceil(len/16)
#define TAB_BYTES ((size_t)NSUBTOT * 8 * 1024)   // 2,449,408
#define OUTELEMS ((size_t)64 * FDIM * 64)        // 2,949,120
#define NCHUNK 80                                // bounded-size work chunks
#define CH 6                                     // max subtiles per chunk

typedef __attribute__((ext_vector_type(8))) short short8;
typedef __attribute__((ext_vector_type(4))) float f32x4;

// pack 2 f32 -> 2 bf16 (round-half-up) in one u32: 2 adds + 1 v_perm
__device__ __forceinline__ uint32_t pkru(float a, float b) {
    uint32_t ua = __builtin_bit_cast(uint32_t, a) + 0x8000u;
    uint32_t ub = __builtin_bit_cast(uint32_t, b) + 0x8000u;
    return __builtin_amdgcn_perm(ub, ua, 0x07060302u);
}
__device__ __forceinline__ short8 loadpack(const float* p) {
    float4 v0 = *(const float4*)p;
    float4 v1 = *(const float4*)(p + 4);
    uint4 u;
    u.x = pkru(v0.x, v0.y);
    u.y = pkru(v0.z, v0.w);
    u.z = pkru(v1.x, v1.y);
    u.w = pkru(v1.z, v1.w);
    return __builtin_bit_cast(short8, u);
}

// partition index / position within part, for partition i at forecast f
__device__ __forceinline__ void jpos(int i, int f, int& j, int& pos) {
    switch (i) {
        case 0: j = 0;       pos = f;            break;
        case 1: j = f / 360; pos = f - 360 * j;  break;
        case 2: j = f / 180; pos = f - 180 * j;  break;
        case 3: j = f / 90;  pos = f - 90 * j;   break;
        case 4: j = f / 45;  pos = f - 45 * j;   break;
        default:
            if (f < 368) { j = f / 23;  pos = f - 23 * j; }
            else { int g = f - 368; int q = g / 22; j = 16 + q; pos = g - 22 * q; }
            break;
    }
}

// per-token parameters (branchy: no runtime-indexed arrays -> no scratch)
__device__ __forceinline__ void tok_params(int tok, int& len, int& ns,
                                           int& start, int& tabsub) {
    if (tok < 1)       { len = 720; ns = 45; start = 0;
                         tabsub = 0; }
    else if (tok < 3)  { int j = tok - 1;  len = 360; ns = 23; start = 360 * j;
                         tabsub = 45 + j * 23; }
    else if (tok < 7)  { int j = tok - 3;  len = 180; ns = 12; start = 180 * j;
                         tabsub = 91 + j * 12; }
    else if (tok < 15) { int j = tok - 7;  len = 90;  ns = 6;  start = 90 * j;
                         tabsub = 139 + j * 6; }
    else if (tok < 31) { int j = tok - 15; len = 45;  ns = 3;  start = 45 * j;
                         tabsub = 187 + j * 3; }
    else               { int j = tok - 31;
                         len = (j < 16) ? 23 : 22;
                         start = (j < 16) ? 23 * j : 368 + 22 * (j - 16);
                         ns = 2; tabsub = 235 + j * 2; }
}

// chunk id -> (token, first subtile)
__device__ __forceinline__ void chunk_params(int cid, int& tok, int& s0) {
    if (cid < 8)       { tok = 0;               s0 = CH * cid; }
    else if (cid < 16) { int q = cid - 8;  tok = 1 + (q >> 2); s0 = CH * (q & 3); }
    else if (cid < 24) { int q = cid - 16; tok = 3 + (q >> 1); s0 = CH * (q & 1); }
    else if (cid < 32) { tok = 7 + (cid - 24);  s0 = 0; }
    else if (cid < 48) { tok = 15 + (cid - 32); s0 = 0; }
    else               { tok = 31 + (cid - 48); s0 = 0; }
}

// ---------------------------------------------------------------------------
// Prep: build bf16 W fragment table in d_ws.
// frag fid = (tabsub(i,j) + s)*8 + ks; lane*16B holds
// W_i[s*16+(lane&15)][ks*32+(lane>>4)*8 ..+8) as bf16 (zeros if row >= len).
// ---------------------------------------------------------------------------
__global__ __launch_bounds__(256) void olrs_prep(
    const float* __restrict__ W0, const float* __restrict__ W1,
    const float* __restrict__ W2, const float* __restrict__ W3,
    const float* __restrict__ W4, const float* __restrict__ W5,
    char* __restrict__ ws)
{
    const int gid  = blockIdx.x * 256 + threadIdx.x;
    const int lane = gid & 63;
    const int fid  = gid >> 6;
    if (fid >= NSUBTOT * 8) return;
    const int ks = fid & 7;
    const int g  = fid >> 3;      // global subtile 0..298

    int len; const float* W;
    int s;
    if (g < 45)       { W = W0; len = 720; s = g; }
    else if (g < 91)  { int g2 = g - 45;  W = W1; len = 360; s = g2 % 23; }
    else if (g < 139) { int g2 = g - 91;  W = W2; len = 180; s = g2 % 12; }
    else if (g < 187) { int g2 = g - 139; W = W3; len = 90;  s = g2 % 6; }
    else if (g < 235) { int g2 = g - 187; W = W4; len = 45;  s = g2 % 3; }
    else              { int g2 = g - 235; W = W5; int j = g2 >> 1;
                        len = (j < 16) ? 23 : 22; s = g2 & 1; }

    const int m15  = lane & 15;
    const int koct = lane >> 4;
    const int pos  = s * 16 + m15;
    uint4 u = {0u, 0u, 0u, 0u};
    if (pos < len) {
        const float* src = W + (size_t)pos * DDIM + ks * 32 + koct * 8;
        float4 v0 = *(const float4*)src;
        float4 v1 = *(const float4*)(src + 4);
        u.x = pkru(v0.x, v0.y);
        u.y = pkru(v0.z, v0.w);
        u.z = pkru(v1.x, v1.y);
        u.w = pkru(v1.z, v1.w);
    }
    *(uint4*)(ws + (size_t)fid * 1024 + lane * 16) = u;
}

// ---------------------------------------------------------------------------
// Init: out[b,f,c] = sum_i b_i[pos(i,f)]  (full overwrite -> replay-safe)
// float4 per thread.
// ---------------------------------------------------------------------------
__global__ __launch_bounds__(256) void olrs_init(
    const float* __restrict__ b0, const float* __restrict__ b1,
    const float* __restrict__ b2, const float* __restrict__ b3,
    const float* __restrict__ b4, const float* __restrict__ b5,
    float* __restrict__ out)
{
    const size_t base = ((size_t)blockIdx.x * 256 + threadIdx.x) * 4;
    if (base >= OUTELEMS) return;
    const int f = (int)((base >> 6) % FDIM);
    int j, p;
    float s = b0[f];
    jpos(1, f, j, p); s += b1[p];
    jpos(2, f, j, p); s += b2[p];
    jpos(3, f, j, p); s += b3[p];
    jpos(4, f, j, p); s += b4[p];
    jpos(5, f, j, p); s += b5[p];
    float4 o = {s, s, s, s};
    *(float4*)(out + base) = o;
}

// ---------------------------------------------------------------------------
// Main: wave = (chunk cid, ntile). x token in registers, sweep <=6
// f-subtiles, atomicAdd contributions into out.
// ---------------------------------------------------------------------------
__global__ __launch_bounds__(256) void olrs_main_at(
    const float* __restrict__ x,
    const char* __restrict__ ws,
    float* __restrict__ out)
{
    const int wid   = blockIdx.x * 4 + (threadIdx.x >> 6);
    const int lane  = threadIdx.x & 63;
    const int cid   = wid >> 8;      // 0..79
    const int ntile = wid & 255;
    const int b     = ntile >> 2;
    const int c0    = (ntile & 3) << 4;
    const int m15   = lane & 15;
    const int koct  = lane >> 4;

    int tok, s0;
    chunk_params(cid, tok, s0);
    int len, ns, start, tabsub;
    tok_params(tok, len, ns, start, tabsub);
    const int send = (s0 + CH < ns) ? (s0 + CH) : ns;

    // ---- load this wave's x token once: 16c x 256d fp32 -> bf16 frags
    const float* xp = x + (((size_t)(b * 64 + c0 + m15)) * TDIM + tok) * DDIM;
    short8 xf[8];
    #pragma unroll
    for (int ks = 0; ks < 8; ks++)
        xf[ks] = loadpack(xp + ks * 32 + koct * 8);

    const char* tab = ws + (size_t)tabsub * 8192 + lane * 16;
    float* obase = out + ((size_t)b * FDIM + start) * 64 + c0 + m15;

    for (int s = s0; s < send; s++) {
        f32x4 a0 = {0.f, 0.f, 0.f, 0.f};
        f32x4 a1 = {0.f, 0.f, 0.f, 0.f};
        const char* tsub = tab + (size_t)s * 8192;
        #pragma unroll
        for (int ks = 0; ks < 8; ks += 2) {
            short8 w0 = *(const short8*)(tsub + ks * 1024);
            short8 w1 = *(const short8*)(tsub + (ks + 1) * 1024);
            a0 = __builtin_amdgcn_mfma_f32_16x16x32_bf16(w0, xf[ks],     a0, 0, 0, 0);
            a1 = __builtin_amdgcn_mfma_f32_16x16x32_bf16(w1, xf[ks + 1], a1, 0, 0, 0);
        }
        const int fl0 = s * 16 + koct * 4;
        #pragma unroll
        for (int rg = 0; rg < 4; rg++) {
            const int fl = fl0 + rg;
            if (fl < len) atomicAdd(obase + (size_t)fl * 64, a0[rg] + a1[rg]);
        }
    }
}

// ---------------------------------------------------------------------------
// Fallback (tiny ws): wave-independent direct-load kernel (round 3).
// ---------------------------------------------------------------------------
__device__ __forceinline__ int startf(int i, int j) {
    switch (i) {
        case 0: return 0;
        case 1: return 360 * j;
        case 2: return 180 * j;
        case 3: return 90 * j;
        case 4: return 45 * j;
        default: return (j < 16) ? 23 * j : 368 + 22 * (j - 16);
    }
}

__global__ __launch_bounds__(256) void olrs_fb(
    const float* __restrict__ x,
    const float* __restrict__ W0, const float* __restrict__ b0,
    const float* __restrict__ W1, const float* __restrict__ b1,
    const float* __restrict__ W2, const float* __restrict__ b2,
    const float* __restrict__ W3, const float* __restrict__ b3,
    const float* __restrict__ W4, const float* __restrict__ b4,
    const float* __restrict__ W5, const float* __restrict__ b5,
    float* __restrict__ out)
{
    const float* Wp[6] = {W0, W1, W2, W3, W4, W5};
    const float* bp[6] = {b0, b1, b2, b3, b4, b5};
    const int TB[6] = {0, 1, 3, 7, 15, 31};

    const int wid  = blockIdx.x * 4 + (threadIdx.x >> 6);
    const int lane = threadIdx.x & 63;
    const int ft   = wid % 45;
    const int bc   = wid / 45;
    const int b    = bc >> 2;
    const int c0   = (bc & 3) << 4;
    const int f0   = ft << 4;
    const int m15  = lane & 15;
    const int koct = lane >> 4;
    const size_t xrow = (size_t)(b * 64 + c0 + m15) * TDIM;

    f32x4 acc = {0.f, 0.f, 0.f, 0.f};
    #pragma unroll
    for (int i = 0; i < 6; i++) {
        int jlo, plo, jhi, phi;
        jpos(i, f0, jlo, plo);
        jpos(i, f0 + 15, jhi, phi);
        const bool cross = (jhi > jlo);
        const int fb = cross ? (startf(i, jhi) - f0) : 16;
        const float* xlo = x + (xrow + TB[i] + jlo) * DDIM;
        const float* xhi = x + (xrow + TB[i] + jhi) * DDIM;
        int jw, pw;
        jpos(i, f0 + m15, jw, pw);
        const float* wsrc = Wp[i] + (size_t)pw * DDIM;
        #pragma unroll
        for (int ks = 0; ks < 8; ks++) {
            const int d0 = ks * 32 + koct * 8;
            short8 a = loadpack(wsrc + d0);
            short8 blo = loadpack(xlo + d0);
            if (!cross) {
                acc = __builtin_amdgcn_mfma_f32_16x16x32_bf16(a, blo, acc, 0, 0, 0);
            } else {
                short8 bhi = loadpack(xhi + d0);
                short8 z;
                #pragma unroll
                for (int q = 0; q < 8; q++) z[q] = 0;
                short8 alo = (m15 < fb) ? a : z;
                short8 ahi = (m15 < fb) ? z : a;
                acc = __builtin_amdgcn_mfma_f32_16x16x32_bf16(alo, blo, acc, 0, 0, 0);
                acc = __builtin_amdgcn_mfma_f32_16x16x32_bf16(ahi, bhi, acc, 0, 0, 0);
            }
        }
    }
    #pragma unroll
    for (int rg = 0; rg < 4; rg++) {
        const int f = f0 + koct * 4 + rg;
        float bias = 0.f;
        #pragma unroll
        for (int i = 0; i < 6; i++) {
            int j, pos;
            jpos(i, f, j, pos);
            bias += bp[i][pos];
        }
        out[((size_t)b * FDIM + f) * 64 + c0 + m15] = acc[rg] + bias;
    }
}

extern "C" void kernel_launch(void* const* d_in, const int* in_sizes, int n_in,
                              void* d_out, int out_size, void* d_ws, size_t ws_size,
                              hipStream_t stream) {
    (void)in_sizes; (void)n_in; (void)out_size;

    const float* x  = (const float*)d_in[0];
    const float* W0 = (const float*)d_in[1];
    const float* b0 = (const float*)d_in[2];
    const float* W1 = (const float*)d_in[3];
    const float* b1 = (const float*)d_in[4];
    const float* W2 = (const float*)d_in[5];
    const float* b2 = (const float*)d_in[6];
    const float* W3 = (const float*)d_in[7];
    const float* b3 = (const float*)d_in[8];
    const float* W4 = (const float*)d_in[9];
    const float* b4 = (const float*)d_in[10];
    const float* W5 = (const float*)d_in[11];
    const float* b5 = (const float*)d_in[12];
    float* out = (float*)d_out;

    if (ws_size >= TAB_BYTES) {
        char* ws = (char*)d_ws;
        olrs_prep<<<dim3(NSUBTOT * 8 * 64 / 256), dim3(256), 0, stream>>>(
            W0, W1, W2, W3, W4, W5, ws);
        olrs_init<<<dim3((unsigned)(OUTELEMS / 4 / 256)), dim3(256), 0, stream>>>(
            b0, b1, b2, b3, b4, b5, out);
        olrs_main_at<<<dim3(NCHUNK * 256 / 4), dim3(256), 0, stream>>>(x, ws, out);
    } else {
        olrs_fb<<<dim3(45 * 256), dim3(256), 0, stream>>>(
            x, W0, b0, W1, b1, W2, b2, W3, b3, W4, b4, W5, b5, out);
    }
}

// Round 7
// 91.662 us; speedup vs baseline: 1.5020x; 1.1367x over previous
//
#include <hip/hip_runtime.h>
#include <stdint.h>

// ---------------------------------------------------------------------------
// OutputLayerReverseSegments, round 7: c=32 waves + W prefetch + HW atomics.
// out[b,f,c] = sum_i x[b,c,t_i(f),:] . W_i[p_i(f),:] + sum_i b_i[p_i(f)]
// B=64, C=64, T=63, D=256, F=720, partitions k = {1,2,4,8,16,32}
//
// Wave = (chunk of <=6 f-subtiles, 32-c tile): loads its token's 32c x 256d
// x-slab once into bf16 register fragments, sweeps subtiles vs the
// pre-packed bf16 W fragment table (2.4 MB, L2-resident; each W frag feeds
// TWO MFMAs -> W request volume halved vs round 6), 2-deep software
// prefetch of the next subtile's W frags, unsafeAtomicAdd (HW
// global_atomic_add_f32, not CAS) into out. Init kernel pre-writes
// out = bias(f) (full overwrite -> replay-safe).
// ---------------------------------------------------------------------------

#define FDIM 720
#define DDIM 256
#define TDIM 63
#define NSUBTOT 299                              // sum over (i,j) of ceil(len/16)
#define TAB_BYTES ((size_t)NSUBTOT * 8 * 1024)   // 2,449,408
#define OUTELEMS ((size_t)64 * FDIM * 64)        // 2,949,120
#define NCHUNK 80                                // bounded-size work chunks
#define CH 6                                     // max subtiles per chunk

typedef __attribute__((ext_vector_type(8))) short short8;
typedef __attribute__((ext_vector_type(4))) float f32x4;

// pack 2 f32 -> 2 bf16 (round-half-up) in one u32: 2 adds + 1 v_perm
__device__ __forceinline__ uint32_t pkru(float a, float b) {
    uint32_t ua = __builtin_bit_cast(uint32_t, a) + 0x8000u;
    uint32_t ub = __builtin_bit_cast(uint32_t, b) + 0x8000u;
    return __builtin_amdgcn_perm(ub, ua, 0x07060302u);
}
__device__ __forceinline__ short8 loadpack(const float* p) {
    float4 v0 = *(const float4*)p;
    float4 v1 = *(const float4*)(p + 4);
    uint4 u;
    u.x = pkru(v0.x, v0.y);
    u.y = pkru(v0.z, v0.w);
    u.z = pkru(v1.x, v1.y);
    u.w = pkru(v1.z, v1.w);
    return __builtin_bit_cast(short8, u);
}

// HW float atomic add (avoid possible CAS-loop lowering of atomicAdd)
__device__ __forceinline__ void atomAddF(float* p, float v) {
    unsafeAtomicAdd(p, v);
}

// partition index / position within part, for partition i at forecast f
__device__ __forceinline__ void jpos(int i, int f, int& j, int& pos) {
    switch (i) {
        case 0: j = 0;       pos = f;            break;
        case 1: j = f / 360; pos = f - 360 * j;  break;
        case 2: j = f / 180; pos = f - 180 * j;  break;
        case 3: j = f / 90;  pos = f - 90 * j;   break;
        case 4: j = f / 45;  pos = f - 45 * j;   break;
        default:
            if (f < 368) { j = f / 23;  pos = f - 23 * j; }
            else { int g = f - 368; int q = g / 22; j = 16 + q; pos = g - 22 * q; }
            break;
    }
}

// per-token parameters (branchy: no runtime-indexed arrays -> no scratch)
__device__ __forceinline__ void tok_params(int tok, int& len, int& ns,
                                           int& start, int& tabsub) {
    if (tok < 1)       { len = 720; ns = 45; start = 0;
                         tabsub = 0; }
    else if (tok < 3)  { int j = tok - 1;  len = 360; ns = 23; start = 360 * j;
                         tabsub = 45 + j * 23; }
    else if (tok < 7)  { int j = tok - 3;  len = 180; ns = 12; start = 180 * j;
                         tabsub = 91 + j * 12; }
    else if (tok < 15) { int j = tok - 7;  len = 90;  ns = 6;  start = 90 * j;
                         tabsub = 139 + j * 6; }
    else if (tok < 31) { int j = tok - 15; len = 45;  ns = 3;  start = 45 * j;
                         tabsub = 187 + j * 3; }
    else               { int j = tok - 31;
                         len = (j < 16) ? 23 : 22;
                         start = (j < 16) ? 23 * j : 368 + 22 * (j - 16);
                         ns = 2; tabsub = 235 + j * 2; }
}

// chunk id -> (token, first subtile)
__device__ __forceinline__ void chunk_params(int cid, int& tok, int& s0) {
    if (cid < 8)       { tok = 0;               s0 = CH * cid; }
    else if (cid < 16) { int q = cid - 8;  tok = 1 + (q >> 2); s0 = CH * (q & 3); }
    else if (cid < 24) { int q = cid - 16; tok = 3 + (q >> 1); s0 = CH * (q & 1); }
    else if (cid < 32) { tok = 7 + (cid - 24);  s0 = 0; }
    else if (cid < 48) { tok = 15 + (cid - 32); s0 = 0; }
    else               { tok = 31 + (cid - 48); s0 = 0; }
}

// ---------------------------------------------------------------------------
// Prep: build bf16 W fragment table in d_ws.
// frag fid = (tabsub(i,j) + s)*8 + ks; lane*16B holds
// W_i[s*16+(lane&15)][ks*32+(lane>>4)*8 ..+8) as bf16 (zeros if row >= len).
// ---------------------------------------------------------------------------
__global__ __launch_bounds__(256) void olrs_prep(
    const float* __restrict__ W0, const float* __restrict__ W1,
    const float* __restrict__ W2, const float* __restrict__ W3,
    const float* __restrict__ W4, const float* __restrict__ W5,
    char* __restrict__ ws)
{
    const int gid  = blockIdx.x * 256 + threadIdx.x;
    const int lane = gid & 63;
    const int fid  = gid >> 6;
    if (fid >= NSUBTOT * 8) return;
    const int ks = fid & 7;
    const int g  = fid >> 3;      // global subtile 0..298

    int len; const float* W;
    int s;
    if (g < 45)       { W = W0; len = 720; s = g; }
    else if (g < 91)  { int g2 = g - 45;  W = W1; len = 360; s = g2 % 23; }
    else if (g < 139) { int g2 = g - 91;  W = W2; len = 180; s = g2 % 12; }
    else if (g < 187) { int g2 = g - 139; W = W3; len = 90;  s = g2 % 6; }
    else if (g < 235) { int g2 = g - 187; W = W4; len = 45;  s = g2 % 3; }
    else              { int g2 = g - 235; W = W5; int j = g2 >> 1;
                        len = (j < 16) ? 23 : 22; s = g2 & 1; }

    const int m15  = lane & 15;
    const int koct = lane >> 4;
    const int pos  = s * 16 + m15;
    uint4 u = {0u, 0u, 0u, 0u};
    if (pos < len) {
        const float* src = W + (size_t)pos * DDIM + ks * 32 + koct * 8;
        float4 v0 = *(const float4*)src;
        float4 v1 = *(const float4*)(src + 4);
        u.x = pkru(v0.x, v0.y);
        u.y = pkru(v0.z, v0.w);
        u.z = pkru(v1.x, v1.y);
        u.w = pkru(v1.z, v1.w);
    }
    *(uint4*)(ws + (size_t)fid * 1024 + lane * 16) = u;
}

// ---------------------------------------------------------------------------
// Init: out[b,f,c] = sum_i b_i[pos(i,f)]  (full overwrite -> replay-safe)
// ---------------------------------------------------------------------------
__global__ __launch_bounds__(256) void olrs_init(
    const float* __restrict__ b0, const float* __restrict__ b1,
    const float* __restrict__ b2, const float* __restrict__ b3,
    const float* __restrict__ b4, const float* __restrict__ b5,
    float* __restrict__ out)
{
    const size_t base = ((size_t)blockIdx.x * 256 + threadIdx.x) * 4;
    if (base >= OUTELEMS) return;
    const int f = (int)((base >> 6) % FDIM);
    int j, p;
    float s = b0[f];
    jpos(1, f, j, p); s += b1[p];
    jpos(2, f, j, p); s += b2[p];
    jpos(3, f, j, p); s += b3[p];
    jpos(4, f, j, p); s += b4[p];
    jpos(5, f, j, p); s += b5[p];
    float4 o = {s, s, s, s};
    *(float4*)(out + base) = o;
}

// ---------------------------------------------------------------------------
// Main: wave = (chunk cid, 32-c tile). x slab in registers, 2-deep W
// prefetch, HW atomics into out.
// ---------------------------------------------------------------------------
__global__ __launch_bounds__(256) void olrs_main_at(
    const float* __restrict__ x,
    const char* __restrict__ ws,
    float* __restrict__ out)
{
    const int wid   = blockIdx.x * 4 + (threadIdx.x >> 6);
    const int lane  = threadIdx.x & 63;
    const int cid   = wid >> 7;      // 0..79
    const int ntile = wid & 127;     // (b, c-half)
    const int b     = ntile >> 1;
    const int c0    = (ntile & 1) << 5;
    const int m15   = lane & 15;
    const int koct  = lane >> 4;

    int tok, s0;
    chunk_params(cid, tok, s0);
    int len, ns, start, tabsub;
    tok_params(tok, len, ns, start, tabsub);
    const int send = (s0 + CH < ns) ? (s0 + CH) : ns;

    // ---- load this wave's x slab once: 32c x 256d fp32 -> bf16 frags
    const float* xpl = x + (((size_t)(b * 64 + c0 + m15)) * TDIM + tok) * DDIM;
    const float* xph = xpl + (size_t)16 * TDIM * DDIM;
    short8 xl[8], xh[8];
    #pragma unroll
    for (int ks = 0; ks < 8; ks++)
        xl[ks] = loadpack(xpl + ks * 32 + koct * 8);
    #pragma unroll
    for (int ks = 0; ks < 8; ks++)
        xh[ks] = loadpack(xph + ks * 32 + koct * 8);

    const char* tab = ws + (size_t)tabsub * 8192 + lane * 16;
    float* obl = out + ((size_t)b * FDIM + start) * 64 + c0 + m15;
    float* obh = obl + 16;

    short8 wA[8], wB[8];

    auto loadW = [&](short8* w, int s) {
        const char* t = tab + (size_t)s * 8192;
        #pragma unroll
        for (int ks = 0; ks < 8; ks++)
            w[ks] = *(const short8*)(t + ks * 1024);
    };
    auto compute = [&](const short8* w, int s) {
        f32x4 al0 = {0.f, 0.f, 0.f, 0.f}, al1 = {0.f, 0.f, 0.f, 0.f};
        f32x4 ah0 = {0.f, 0.f, 0.f, 0.f}, ah1 = {0.f, 0.f, 0.f, 0.f};
        #pragma unroll
        for (int ks = 0; ks < 8; ks += 2) {
            al0 = __builtin_amdgcn_mfma_f32_16x16x32_bf16(w[ks],     xl[ks],     al0, 0, 0, 0);
            ah0 = __builtin_amdgcn_mfma_f32_16x16x32_bf16(w[ks],     xh[ks],     ah0, 0, 0, 0);
            al1 = __builtin_amdgcn_mfma_f32_16x16x32_bf16(w[ks + 1], xl[ks + 1], al1, 0, 0, 0);
            ah1 = __builtin_amdgcn_mfma_f32_16x16x32_bf16(w[ks + 1], xh[ks + 1], ah1, 0, 0, 0);
        }
        const int fl0 = s * 16 + koct * 4;
        #pragma unroll
        for (int rg = 0; rg < 4; rg++) {
            const int fl = fl0 + rg;
            if (fl < len) {
                atomAddF(obl + (size_t)fl * 64, al0[rg] + al1[rg]);
                atomAddF(obh + (size_t)fl * 64, ah0[rg] + ah1[rg]);
            }
        }
    };

    // ---- 2-deep pipelined sweep over subtiles
    int s = s0;
    loadW(wA, s);
    for (;;) {
        if (s + 1 < send) loadW(wB, s + 1);
        compute(wA, s);
        if (++s >= send) break;
        if (s + 1 < send) loadW(wA, s + 1);
        compute(wB, s);
        if (++s >= send) break;
    }
}

// ---------------------------------------------------------------------------
// Fallback (tiny ws): wave-independent direct-load kernel (round 3).
// ---------------------------------------------------------------------------
__device__ __forceinline__ int startf(int i, int j) {
    switch (i) {
        case 0: return 0;
        case 1: return 360 * j;
        case 2: return 180 * j;
        case 3: return 90 * j;
        case 4: return 45 * j;
        default: return (j < 16) ? 23 * j : 368 + 22 * (j - 16);
    }
}

__global__ __launch_bounds__(256) void olrs_fb(
    const float* __restrict__ x,
    const float* __restrict__ W0, const float* __restrict__ b0,
    const float* __restrict__ W1, const float* __restrict__ b1,
    const float* __restrict__ W2, const float* __restrict__ b2,
    const float* __restrict__ W3, const float* __restrict__ b3,
    const float* __restrict__ W4, const float* __restrict__ b4,
    const float* __restrict__ W5, const float* __restrict__ b5,
    float* __restrict__ out)
{
    const float* Wp[6] = {W0, W1, W2, W3, W4, W5};
    const float* bp[6] = {b0, b1, b2, b3, b4, b5};
    const int TB[6] = {0, 1, 3, 7, 15, 31};

    const int wid  = blockIdx.x * 4 + (threadIdx.x >> 6);
    const int lane = threadIdx.x & 63;
    const int ft   = wid % 45;
    const int bc   = wid / 45;
    const int b    = bc >> 2;
    const int c0   = (bc & 3) << 4;
    const int f0   = ft << 4;
    const int m15  = lane & 15;
    const int koct = lane >> 4;
    const size_t xrow = (size_t)(b * 64 + c0 + m15) * TDIM;

    f32x4 acc = {0.f, 0.f, 0.f, 0.f};
    #pragma unroll
    for (int i = 0; i < 6; i++) {
        int jlo, plo, jhi, phi;
        jpos(i, f0, jlo, plo);
        jpos(i, f0 + 15, jhi, phi);
        const bool cross = (jhi > jlo);
        const int fb = cross ? (startf(i, jhi) - f0) : 16;
        const float* xlo = x + (xrow + TB[i] + jlo) * DDIM;
        const float* xhi = x + (xrow + TB[i] + jhi) * DDIM;
        int jw, pw;
        jpos(i, f0 + m15, jw, pw);
        const float* wsrc = Wp[i] + (size_t)pw * DDIM;
        #pragma unroll
        for (int ks = 0; ks < 8; ks++) {
            const int d0 = ks * 32 + koct * 8;
            short8 a = loadpack(wsrc + d0);
            short8 blo = loadpack(xlo + d0);
            if (!cross) {
                acc = __builtin_amdgcn_mfma_f32_16x16x32_bf16(a, blo, acc, 0, 0, 0);
            } else {
                short8 bhi = loadpack(xhi + d0);
                short8 z;
                #pragma unroll
                for (int q = 0; q < 8; q++) z[q] = 0;
                short8 alo = (m15 < fb) ? a : z;
                short8 ahi = (m15 < fb) ? z : a;
                acc = __builtin_amdgcn_mfma_f32_16x16x32_bf16(alo, blo, acc, 0, 0, 0);
                acc = __builtin_amdgcn_mfma_f32_16x16x32_bf16(ahi, bhi, acc, 0, 0, 0);
            }
        }
    }
    #pragma unroll
    for (int rg = 0; rg < 4; rg++) {
        const int f = f0 + koct * 4 + rg;
        float bias = 0.f;
        #pragma unroll
        for (int i = 0; i < 6; i++) {
            int j, pos;
            jpos(i, f, j, pos);
            bias += bp[i][pos];
        }
        out[((size_t)b * FDIM + f) * 64 + c0 + m15] = acc[rg] + bias;
    }
}

extern "C" void kernel_launch(void* const* d_in, const int* in_sizes, int n_in,
                              void* d_out, int out_size, void* d_ws, size_t ws_size,
                              hipStream_t stream) {
    (void)in_sizes; (void)n_in; (void)out_size;

    const float* x  = (const float*)d_in[0];
    const float* W0 = (const float*)d_in[1];
    const float* b0 = (const float*)d_in[2];
    const float* W1 = (const float*)d_in[3];
    const float* b1 = (const float*)d_in[4];
    const float* W2 = (const float*)d_in[5];
    const float* b2 = (const float*)d_in[6];
    const float* W3 = (const float*)d_in[7];
    const float* b3 = (const float*)d_in[8];
    const float* W4 = (const float*)d_in[9];
    const float* b4 = (const float*)d_in[10];
    const float* W5 = (const float*)d_in[11];
    const float* b5 = (const float*)d_in[12];
    float* out = (float*)d_out;

    if (ws_size >= TAB_BYTES) {
        char* ws = (char*)d_ws;
        olrs_prep<<<dim3(NSUBTOT * 8 * 64 / 256), dim3(256), 0, stream>>>(
            W0, W1, W2, W3, W4, W5, ws);
        olrs_init<<<dim3((unsigned)(OUTELEMS / 4 / 256)), dim3(256), 0, stream>>>(
            b0, b1, b2, b3, b4, b5, out);
        olrs_main_at<<<dim3(NCHUNK * 128 / 4), dim3(256), 0, stream>>>(x, ws, out);
    } else {
        olrs_fb<<<dim3(45 * 256), dim3(256), 0, stream>>>(
            x, W0, b0, W1, b1, W2, b2, W3, b3, W4, b4, W5, b5, out);
    }
}

// Round 8
// 86.928 us; speedup vs baseline: 1.5838x; 1.0545x over previous
//
#include <hip/hip_runtime.h>
#include <stdint.h>

// ---------------------------------------------------------------------------
// OutputLayerReverseSegments, round 8: token-major, LDS-shared x for split
// tokens, fused prep+init, HW atomics.
// out[b,f,c] = sum_i x[b,c,t_i(f),:] . W_i[p_i(f),:] + sum_i b_i[p_i(f)]
// B=64, C=64, T=63, D=256, F=720, partitions k = {1,2,4,8,16,32}
//
// Grid: 20 roles x 128 (b, c-half) tiles = 2560 blocks x 4 waves.
//  roles 0-1 : tok0 (8 chunks of <=6 subtiles, 2 blocks, LDS-shared slab)
//  roles 2-3 : tok1, tok2 (4 chunks each, LDS-shared)
//  roles 4-5 : tok{3,4}, tok{5,6} (2 chunks each, 2 LDS slabs per block)
//  roles 6-19: tok7..62 (1 chunk per wave, register path, no LDS)
// Shared-x blocks stage the 32c x 256d fp32 slab -> bf16 LDS in MFMA
// fragment order (read back linear lane*16B -> conflict-free), so x HBM
// traffic = 264 MB + 4 MB (tok0 2-block dup). W from pre-packed bf16
// fragment table (2.4 MB, L2-resident), 2-deep prefetch, each frag feeds
// two MFMAs (c-lo/c-hi). unsafeAtomicAdd merges partitions into out;
// fused prep+init kernel packs W and pre-writes out = bias(f).
// ---------------------------------------------------------------------------

#define FDIM 720
#define DDIM 256
#define TDIM 63
#define NSUBTOT 299                              // sum over (i,j) of ceil(len/16)
#define TAB_BYTES ((size_t)NSUBTOT * 8 * 1024)   // 2,449,408
#define OUTELEMS ((size_t)64 * FDIM * 64)        // 2,949,120
#define NPREPTHR (NSUBTOT * 8 * 64)              // 153,088

typedef __attribute__((ext_vector_type(8))) short short8;
typedef __attribute__((ext_vector_type(4))) float f32x4;

// pack 2 f32 -> 2 bf16 (round-half-up) in one u32: 2 adds + 1 v_perm
__device__ __forceinline__ uint32_t pkru(float a, float b) {
    uint32_t ua = __builtin_bit_cast(uint32_t, a) + 0x8000u;
    uint32_t ub = __builtin_bit_cast(uint32_t, b) + 0x8000u;
    return __builtin_amdgcn_perm(ub, ua, 0x07060302u);
}
__device__ __forceinline__ short8 loadpack(const float* p) {
    float4 v0 = *(const float4*)p;
    float4 v1 = *(const float4*)(p + 4);
    uint4 u;
    u.x = pkru(v0.x, v0.y);
    u.y = pkru(v0.z, v0.w);
    u.z = pkru(v1.x, v1.y);
    u.w = pkru(v1.z, v1.w);
    return __builtin_bit_cast(short8, u);
}

// HW float atomic add (avoid CAS-loop lowering)
__device__ __forceinline__ void atomAddF(float* p, float v) {
    unsafeAtomicAdd(p, v);
}

// partition index / position within part, for partition i at forecast f
__device__ __forceinline__ void jpos(int i, int f, int& j, int& pos) {
    switch (i) {
        case 0: j = 0;       pos = f;            break;
        case 1: j = f / 360; pos = f - 360 * j;  break;
        case 2: j = f / 180; pos = f - 180 * j;  break;
        case 3: j = f / 90;  pos = f - 90 * j;   break;
        case 4: j = f / 45;  pos = f - 45 * j;   break;
        default:
            if (f < 368) { j = f / 23;  pos = f - 23 * j; }
            else { int g = f - 368; int q = g / 22; j = 16 + q; pos = g - 22 * q; }
            break;
    }
}

// per-token parameters
__device__ __forceinline__ void tok_params(int tok, int& len, int& ns,
                                           int& start, int& tabsub) {
    if (tok < 1)       { len = 720; ns = 45; start = 0;
                         tabsub = 0; }
    else if (tok < 3)  { int j = tok - 1;  len = 360; ns = 23; start = 360 * j;
                         tabsub = 45 + j * 23; }
    else if (tok < 7)  { int j = tok - 3;  len = 180; ns = 12; start = 180 * j;
                         tabsub = 91 + j * 12; }
    else if (tok < 15) { int j = tok - 7;  len = 90;  ns = 6;  start = 90 * j;
                         tabsub = 139 + j * 6; }
    else if (tok < 31) { int j = tok - 15; len = 45;  ns = 3;  start = 45 * j;
                         tabsub = 187 + j * 3; }
    else               { int j = tok - 31;
                         len = (j < 16) ? 23 : 22;
                         start = (j < 16) ? 23 * j : 368 + 22 * (j - 16);
                         ns = 2; tabsub = 235 + j * 2; }
}

// ---------------------------------------------------------------------------
// Fused prep + init.
//  - every thread writes one float4 of out = bias(f)   (full overwrite)
//  - threads with gid < NPREPTHR also pack one W fragment into d_ws
// ---------------------------------------------------------------------------
__global__ __launch_bounds__(256) void olrs_prepinit(
    const float* __restrict__ W0, const float* __restrict__ W1,
    const float* __restrict__ W2, const float* __restrict__ W3,
    const float* __restrict__ W4, const float* __restrict__ W5,
    const float* __restrict__ b0, const float* __restrict__ b1,
    const float* __restrict__ b2, const float* __restrict__ b3,
    const float* __restrict__ b4, const float* __restrict__ b5,
    char* __restrict__ ws, float* __restrict__ out)
{
    const int gid = blockIdx.x * 256 + threadIdx.x;

    // ---- init section
    const size_t base = (size_t)gid * 4;
    if (base < OUTELEMS) {
        const int f = (int)((base >> 6) % FDIM);
        int j, p;
        float s = b0[f];
        jpos(1, f, j, p); s += b1[p];
        jpos(2, f, j, p); s += b2[p];
        jpos(3, f, j, p); s += b3[p];
        jpos(4, f, j, p); s += b4[p];
        jpos(5, f, j, p); s += b5[p];
        float4 o = {s, s, s, s};
        *(float4*)(out + base) = o;
    }

    // ---- prep section
    if (gid < NPREPTHR) {
        const int lane = gid & 63;
        const int fid  = gid >> 6;
        const int ks = fid & 7;
        const int g  = fid >> 3;      // global subtile 0..298

        int len; const float* W; int s;
        if (g < 45)       { W = W0; len = 720; s = g; }
        else if (g < 91)  { int g2 = g - 45;  W = W1; len = 360; s = g2 % 23; }
        else if (g < 139) { int g2 = g - 91;  W = W2; len = 180; s = g2 % 12; }
        else if (g < 187) { int g2 = g - 139; W = W3; len = 90;  s = g2 % 6; }
        else if (g < 235) { int g2 = g - 187; W = W4; len = 45;  s = g2 % 3; }
        else              { int g2 = g - 235; W = W5; int j = g2 >> 1;
                            len = (j < 16) ? 23 : 22; s = g2 & 1; }

        const int m15  = lane & 15;
        const int koct = lane >> 4;
        const int pos  = s * 16 + m15;
        uint4 u = {0u, 0u, 0u, 0u};
        if (pos < len) {
            const float* src = W + (size_t)pos * DDIM + ks * 32 + koct * 8;
            float4 v0 = *(const float4*)src;
            float4 v1 = *(const float4*)(src + 4);
            u.x = pkru(v0.x, v0.y);
            u.y = pkru(v0.z, v0.w);
            u.z = pkru(v1.x, v1.y);
            u.w = pkru(v1.z, v1.w);
        }
        *(uint4*)(ws + (size_t)fid * 1024 + lane * 16) = u;
    }
}

// ---------------------------------------------------------------------------
// Main: role-encoded blocks; LDS-shared x for split tokens.
// LDS slab layout (per 16 KB slab): fragment order —
//   addr = ((ks*2 + h)*64 + lane)*16 holds x[c0 + h*16 + (lane&15)]
//          [ks*32 + (lane>>4)*8 ..+8) as bf16.
// ---------------------------------------------------------------------------
__global__ __launch_bounds__(256) void olrs_main8(
    const float* __restrict__ x,
    const char* __restrict__ ws,
    float* __restrict__ out)
{
    __shared__ char lds[32768];

    const int bid   = blockIdx.x;
    const int rid   = bid >> 7;      // 0..19
    const int ntile = bid & 127;     // (b, c-half)
    const int w     = threadIdx.x >> 6;
    const int lane  = threadIdx.x & 63;
    const int b     = ntile >> 1;
    const int c0    = (ntile & 1) << 5;
    const int m15   = lane & 15;
    const int koct  = lane >> 4;

    // ---- role decode (block-uniform except w-dependence)
    int tok, s0, slab;
    bool shx;
    if (rid < 2)      { tok = 0;            s0 = rid * 24 + w * 6; shx = true;  slab = 0; }
    else if (rid < 4) { tok = rid - 1;      s0 = w * 6;            shx = true;  slab = 0; }
    else if (rid < 6) { int tb = 3 + (rid - 4) * 2;
                        tok = tb + (w >> 1); s0 = (w & 1) * 6;     shx = true;  slab = w >> 1; }
    else              { tok = 7 + (rid - 6) * 4 + w; s0 = 0;       shx = false; slab = 0; }

    int len, ns, start, tabsub;
    tok_params(tok, len, ns, start, tabsub);
    const int send = (s0 + 6 < ns) ? (s0 + 6) : ns;

    // ---- x slab: shared staging or per-wave register load
    short8 xl[8], xh[8];
    if (shx) {
        const int nslab   = (rid >= 4 && rid < 6) ? 2 : 1;
        const int tokbase = (rid < 2) ? 0 : ((rid < 4) ? (rid - 1) : 3 + (rid - 4) * 2);
        const int cc = threadIdx.x >> 3;   // 0..31
        const int t8 = threadIdx.x & 7;    // 0..7
        for (int sl = 0; sl < nslab; sl++) {
            const float* src = x + (((size_t)(b * 64 + c0 + cc)) * TDIM + tokbase + sl) * DDIM;
            char* dst = lds + sl * 16384;
            #pragma unroll
            for (int rep = 0; rep < 4; rep++) {
                const int d8 = t8 + rep * 8;            // 0..31
                float4 v0 = *(const float4*)(src + d8 * 8);
                float4 v1 = *(const float4*)(src + d8 * 8 + 4);
                uint4 u;
                u.x = pkru(v0.x, v0.y);
                u.y = pkru(v0.z, v0.w);
                u.z = pkru(v1.x, v1.y);
                u.w = pkru(v1.z, v1.w);
                // frag addr: ks = d8>>2, koct' = d8&3, h = cc>>4, m15' = cc&15
                const int slot = ((d8 >> 2) * 2 + (cc >> 4)) * 64
                               + (d8 & 3) * 16 + (cc & 15);
                *(uint4*)(dst + slot * 16) = u;
            }
        }
        __syncthreads();
        const char* sb = lds + slab * 16384;
        #pragma unroll
        for (int ks = 0; ks < 8; ks++) {
            xl[ks] = *(const short8*)(sb + ((ks * 2 + 0) * 64 + lane) * 16);
            xh[ks] = *(const short8*)(sb + ((ks * 2 + 1) * 64 + lane) * 16);
        }
    } else {
        const float* xpl = x + (((size_t)(b * 64 + c0 + m15)) * TDIM + tok) * DDIM;
        const float* xph = xpl + (size_t)16 * TDIM * DDIM;
        #pragma unroll
        for (int ks = 0; ks < 8; ks++)
            xl[ks] = loadpack(xpl + ks * 32 + koct * 8);
        #pragma unroll
        for (int ks = 0; ks < 8; ks++)
            xh[ks] = loadpack(xph + ks * 32 + koct * 8);
    }

    const char* tab = ws + (size_t)tabsub * 8192 + lane * 16;
    float* obl = out + ((size_t)b * FDIM + start) * 64 + c0 + m15;
    float* obh = obl + 16;

    short8 wA[8], wB[8];

    auto loadW = [&](short8* wreg, int s) {
        const char* t = tab + (size_t)s * 8192;
        #pragma unroll
        for (int ks = 0; ks < 8; ks++)
            wreg[ks] = *(const short8*)(t + ks * 1024);
    };
    auto compute = [&](const short8* wreg, int s) {
        f32x4 al0 = {0.f, 0.f, 0.f, 0.f}, al1 = {0.f, 0.f, 0.f, 0.f};
        f32x4 ah0 = {0.f, 0.f, 0.f, 0.f}, ah1 = {0.f, 0.f, 0.f, 0.f};
        #pragma unroll
        for (int ks = 0; ks < 8; ks += 2) {
            al0 = __builtin_amdgcn_mfma_f32_16x16x32_bf16(wreg[ks],     xl[ks],     al0, 0, 0, 0);
            ah0 = __builtin_amdgcn_mfma_f32_16x16x32_bf16(wreg[ks],     xh[ks],     ah0, 0, 0, 0);
            al1 = __builtin_amdgcn_mfma_f32_16x16x32_bf16(wreg[ks + 1], xl[ks + 1], al1, 0, 0, 0);
            ah1 = __builtin_amdgcn_mfma_f32_16x16x32_bf16(wreg[ks + 1], xh[ks + 1], ah1, 0, 0, 0);
        }
        const int fl0 = s * 16 + koct * 4;
        #pragma unroll
        for (int rg = 0; rg < 4; rg++) {
            const int fl = fl0 + rg;
            if (fl < len) {
                atomAddF(obl + (size_t)fl * 64, al0[rg] + al1[rg]);
                atomAddF(obh + (size_t)fl * 64, ah0[rg] + ah1[rg]);
            }
        }
    };

    // ---- 2-deep pipelined sweep over subtiles
    int s = s0;
    loadW(wA, s);
    for (;;) {
        if (s + 1 < send) loadW(wB, s + 1);
        compute(wA, s);
        if (++s >= send) break;
        if (s + 1 < send) loadW(wA, s + 1);
        compute(wB, s);
        if (++s >= send) break;
    }
}

// ---------------------------------------------------------------------------
// Fallback (tiny ws): wave-independent direct-load kernel (round 3).
// ---------------------------------------------------------------------------
__device__ __forceinline__ int startf(int i, int j) {
    switch (i) {
        case 0: return 0;
        case 1: return 360 * j;
        case 2: return 180 * j;
        case 3: return 90 * j;
        case 4: return 45 * j;
        default: return (j < 16) ? 23 * j : 368 + 22 * (j - 16);
    }
}

__global__ __launch_bounds__(256) void olrs_fb(
    const float* __restrict__ x,
    const float* __restrict__ W0, const float* __restrict__ b0,
    const float* __restrict__ W1, const float* __restrict__ b1,
    const float* __restrict__ W2, const float* __restrict__ b2,
    const float* __restrict__ W3, const float* __restrict__ b3,
    const float* __restrict__ W4, const float* __restrict__ b4,
    const float* __restrict__ W5, const float* __restrict__ b5,
    float* __restrict__ out)
{
    const float* Wp[6] = {W0, W1, W2, W3, W4, W5};
    const float* bp[6] = {b0, b1, b2, b3, b4, b5};
    const int TB[6] = {0, 1, 3, 7, 15, 31};

    const int wid  = blockIdx.x * 4 + (threadIdx.x >> 6);
    const int lane = threadIdx.x & 63;
    const int ft   = wid % 45;
    const int bc   = wid / 45;
    const int b    = bc >> 2;
    const int c0   = (bc & 3) << 4;
    const int f0   = ft << 4;
    const int m15  = lane & 15;
    const int koct = lane >> 4;
    const size_t xrow = (size_t)(b * 64 + c0 + m15) * TDIM;

    f32x4 acc = {0.f, 0.f, 0.f, 0.f};
    #pragma unroll
    for (int i = 0; i < 6; i++) {
        int jlo, plo, jhi, phi;
        jpos(i, f0, jlo, plo);
        jpos(i, f0 + 15, jhi, phi);
        const bool cross = (jhi > jlo);
        const int fb = cross ? (startf(i, jhi) - f0) : 16;
        const float* xlo = x + (xrow + TB[i] + jlo) * DDIM;
        const float* xhi = x + (xrow + TB[i] + jhi) * DDIM;
        int jw, pw;
        jpos(i, f0 + m15, jw, pw);
        const float* wsrc = Wp[i] + (size_t)pw * DDIM;
        #pragma unroll
        for (int ks = 0; ks < 8; ks++) {
            const int d0 = ks * 32 + koct * 8;
            short8 a = loadpack(wsrc + d0);
            short8 blo = loadpack(xlo + d0);
            if (!cross) {
                acc = __builtin_amdgcn_mfma_f32_16x16x32_bf16(a, blo, acc, 0, 0, 0);
            } else {
                short8 bhi = loadpack(xhi + d0);
                short8 z;
                #pragma unroll
                for (int q = 0; q < 8; q++) z[q] = 0;
                short8 alo = (m15 < fb) ? a : z;
                short8 ahi = (m15 < fb) ? z : a;
                acc = __builtin_amdgcn_mfma_f32_16x16x32_bf16(alo, blo, acc, 0, 0, 0);
                acc = __builtin_amdgcn_mfma_f32_16x16x32_bf16(ahi, bhi, acc, 0, 0, 0);
            }
        }
    }
    #pragma unroll
    for (int rg = 0; rg < 4; rg++) {
        const int f = f0 + koct * 4 + rg;
        float bias = 0.f;
        #pragma unroll
        for (int i = 0; i < 6; i++) {
            int j, pos;
            jpos(i, f, j, pos);
            bias += bp[i][pos];
        }
        out[((size_t)b * FDIM + f) * 64 + c0 + m15] = acc[rg] + bias;
    }
}

extern "C" void kernel_launch(void* const* d_in, const int* in_sizes, int n_in,
                              void* d_out, int out_size, void* d_ws, size_t ws_size,
                              hipStream_t stream) {
    (void)in_sizes; (void)n_in; (void)out_size;

    const float* x  = (const float*)d_in[0];
    const float* W0 = (const float*)d_in[1];
    const float* b0 = (const float*)d_in[2];
    const float* W1 = (const float*)d_in[3];
    const float* b1 = (const float*)d_in[4];
    const float* W2 = (const float*)d_in[5];
    const float* b2 = (const float*)d_in[6];
    const float* W3 = (const float*)d_in[7];
    const float* b3 = (const float*)d_in[8];
    const float* W4 = (const float*)d_in[9];
    const float* b4 = (const float*)d_in[10];
    const float* W5 = (const float*)d_in[11];
    const float* b5 = (const float*)d_in[12];
    float* out = (float*)d_out;

    if (ws_size >= TAB_BYTES) {
        char* ws = (char*)d_ws;
        olrs_prepinit<<<dim3((unsigned)(OUTELEMS / 4 / 256)), dim3(256), 0, stream>>>(
            W0, W1, W2, W3, W4, W5, b0, b1, b2, b3, b4, b5, ws, out);
        olrs_main8<<<dim3(20 * 128), dim3(256), 0, stream>>>(x, ws, out);
    } else {
        olrs_fb<<<dim3(45 * 256), dim3(256), 0, stream>>>(
            x, W0, b0, W1, b1, W2, b2, W3, b3, W4, b4, W5, b5, out);
    }
}